// Round 2
// baseline (524.870 us; speedup 1.0000x reference)
//
#include <hip/hip_runtime.h>

// Problem constants: B=1024, L=64, N=65536, V=100000, E=300, RH=M=50, NC=3
// tree: balanced binary, parent=(i-1)//2, depths 0..6, locs 0..31 have children

typedef __attribute__((ext_vector_type(8))) short bf16x8;
typedef __attribute__((ext_vector_type(4))) float f32x4;

// ---- activations ----
__device__ __forceinline__ float fsig(float x) { return 1.0f / (1.0f + __expf(-x)); }
__device__ __forceinline__ float ftanh(float x) {
    float a = fabsf(x);
    float t = __expf(2.0f * a);
    float r = 1.0f - 2.0f / (t + 1.0f);
    return copysignf(r, x);
}
__device__ __forceinline__ float fsig2(float x) {
    float e = __builtin_amdgcn_exp2f(-1.4426950408889634f * x);
    return __builtin_amdgcn_rcpf(1.0f + e);
}
__device__ __forceinline__ float ftanh2(float x) {
    float e = __builtin_amdgcn_exp2f(2.8853900817779268f * x);
    return 1.0f - 2.0f * __builtin_amdgcn_rcpf(1.0f + e);
}

// round-to-nearest-even f32 -> bf16 (returns upper 16 bits)
__device__ __forceinline__ unsigned short rne_bf16(float f) {
    unsigned u = __builtin_bit_cast(unsigned, f);
    unsigned r = u + 0x7fffu + ((u >> 16) & 1u);
    return (unsigned short)(r >> 16);
}
// fp32 -> bf16 hi + bf16 lo (RNE both limbs; combined residual ~2^-17 rel, unbiased)
__device__ __forceinline__ void split2(float f, unsigned short& h, unsigned short& l) {
    h = rne_bf16(f);
    float fh = __builtin_bit_cast(float, ((unsigned)h) << 16);
    float r = f - fh;   // exact (Sterbenz)
    l = rne_bf16(r);
}

__device__ __forceinline__ void async_lds16(const void* g, void* l) {
    __builtin_amdgcn_global_load_lds(
        (const __attribute__((address_space(1))) unsigned int*)g,
        (__attribute__((address_space(3))) unsigned int*)l, 16, 0, 0);
}

__device__ __forceinline__ bf16x8 pack8(const unsigned short* h) {
    bf16x8 v;
    #pragma unroll
    for (int e = 0; e < 8; ++e) v[e] = (short)h[e];
    return v;
}

// ---------------------------------------------------------------------------
// K0: convert weights [B1;B2] (rows = output cols, K contraction) to chunked
// hi|lo bf16 layout: out[(((c*2+h)*4 + kq)*BN + n)*8 + e] covers
// k = c*32 + kq*8 + e.  n >= Rreal or k >= K zero-filled.
// Linear per chunk (async-copyable) AND lane-consecutive for frag reads.
// Total size per call: KCH*2*4*BN*8 shorts.
// ---------------------------------------------------------------------------
__global__ void conv_kernel(const float* __restrict__ B1, const float* __restrict__ B2,
                            int split, int K, int Rreal, int BN, int KCH,
                            unsigned short* __restrict__ out) {
    int q = blockIdx.x * 256 + threadIdx.x;
    int total = KCH * 4 * BN;
    if (q >= total) return;
    int n  = q % BN;
    int kq = (q / BN) & 3;
    int c  = q / (BN * 4);
    const float* row = (n < split) ? (B1 + (size_t)n * K) : (B2 + (size_t)(n - split) * K);
    unsigned short h[8], l[8];
    #pragma unroll
    for (int e = 0; e < 8; ++e) {
        int k = c * 32 + kq * 8 + e;
        float v = (n < Rreal && k < K) ? row[k] : 0.0f;
        split2(v, h[e], l[e]);
    }
    size_t hb = ((((size_t)c * 2 + 0) * 4 + kq) * BN + n) * 8;
    size_t lb = ((((size_t)c * 2 + 1) * 4 + kq) * BN + n) * 8;
    *(ushort4*)&out[hb]     = make_ushort4(h[0], h[1], h[2], h[3]);
    *(ushort4*)&out[hb + 4] = make_ushort4(h[4], h[5], h[6], h[7]);
    *(ushort4*)&out[lb]     = make_ushort4(l[0], l[1], l[2], l[3]);
    *(ushort4*)&out[lb + 4] = make_ushort4(l[4], l[5], l[6], l[7]);
}

// ---------------------------------------------------------------------------
// Split-bf16 MFMA GEMM. BM=64 rows, BN padded cols, 256 thr = 4 waves
// column-split. Conflict-free LDS: A [h][kq][64][8], B [h][kq][BN][8]
// (pre-converted, async-staged). 3 mfma terms: Ah*Bh + Al*Bh + Ah*Bl.
// ---------------------------------------------------------------------------
template<int BN, int KCH, int KREAL, int NCOLS, bool GATHER>
__global__ __launch_bounds__(256)
void gemm_split(const float* __restrict__ A, const int* __restrict__ ids,
                const unsigned short* __restrict__ Bc,
                const float* __restrict__ bias1, const float* __restrict__ bias2,
                int split, float* __restrict__ C) {
    constexpr int NTW = BN / 64;   // 16-col tiles per wave
    __shared__ __align__(16) unsigned short As[2 * 4 * 64 * 8];  // 8 KB
    __shared__ __align__(16) unsigned short Bt[64 * BN];

    const int tid = threadIdx.x;
    const int m0 = blockIdx.x * 64;
    const int w = tid >> 6, lane = tid & 63;
    const int r16 = lane & 15, quad = lane >> 4;
    const int wn = w * (BN / 4);

    const int mA = tid & 63, kqA = tid >> 6;
    const float* arow = GATHER ? (A + (size_t)ids[m0 + mA] * KREAL)
                               : (A + (size_t)(m0 + mA) * KREAL);

    float ar[8];
    {
        int k0 = kqA * 8;
        if (k0 + 8 <= KREAL) {
            float4 p = *(const float4*)(arow + k0);
            float4 q = *(const float4*)(arow + k0 + 4);
            ar[0]=p.x; ar[1]=p.y; ar[2]=p.z; ar[3]=p.w;
            ar[4]=q.x; ar[5]=q.y; ar[6]=q.z; ar[7]=q.w;
        } else {
            #pragma unroll
            for (int e = 0; e < 8; ++e) ar[e] = (k0 + e < KREAL) ? arow[k0 + e] : 0.0f;
        }
    }

    f32x4 acc[4][NTW] = {};

    for (int c = 0; c < KCH; ++c) {
        __syncthreads();
        {
            const unsigned short* src = Bc + (size_t)c * 64 * BN + tid * 8;
            #pragma unroll
            for (int i = 0; i < BN / 32; ++i)
                async_lds16(src + (size_t)i * 2048, Bt + i * 2048 + tid * 8);
        }
        {
            unsigned short h[8], l[8];
            #pragma unroll
            for (int e = 0; e < 8; ++e) split2(ar[e], h[e], l[e]);
            *(bf16x8*)&As[((0 * 4 + kqA) * 64 + mA) * 8] = pack8(h);
            *(bf16x8*)&As[((1 * 4 + kqA) * 64 + mA) * 8] = pack8(l);
        }
        __syncthreads();
        if (c + 1 < KCH) {
            int k0 = (c + 1) * 32 + kqA * 8;
            if (k0 + 8 <= KREAL) {
                float4 p = *(const float4*)(arow + k0);
                float4 q = *(const float4*)(arow + k0 + 4);
                ar[0]=p.x; ar[1]=p.y; ar[2]=p.z; ar[3]=p.w;
                ar[4]=q.x; ar[5]=q.y; ar[6]=q.z; ar[7]=q.w;
            } else {
                #pragma unroll
                for (int e = 0; e < 8; ++e) ar[e] = (k0 + e < KREAL) ? arow[k0 + e] : 0.0f;
            }
        }
        bf16x8 af[2][4];
        #pragma unroll
        for (int i = 0; i < 4; ++i) {
            af[0][i] = *(const bf16x8*)&As[((0 * 4 + quad) * 64 + i * 16 + r16) * 8];
            af[1][i] = *(const bf16x8*)&As[((1 * 4 + quad) * 64 + i * 16 + r16) * 8];
        }
        #pragma unroll
        for (int t = 0; t < NTW; ++t) {
            bf16x8 bh = *(const bf16x8*)&Bt[((0 * 4 + quad) * BN + wn + t * 16 + r16) * 8];
            bf16x8 bl = *(const bf16x8*)&Bt[((1 * 4 + quad) * BN + wn + t * 16 + r16) * 8];
            #pragma unroll
            for (int i = 0; i < 4; ++i) {
                acc[i][t] = __builtin_amdgcn_mfma_f32_16x16x32_bf16(af[0][i], bh, acc[i][t], 0, 0, 0);
                acc[i][t] = __builtin_amdgcn_mfma_f32_16x16x32_bf16(af[1][i], bh, acc[i][t], 0, 0, 0);
                acc[i][t] = __builtin_amdgcn_mfma_f32_16x16x32_bf16(af[0][i], bl, acc[i][t], 0, 0, 0);
            }
        }
    }

    #pragma unroll
    for (int t = 0; t < NTW; ++t) {
        int ncol = wn + t * 16 + r16;
        if (ncol < NCOLS) {
            float bv = (ncol < split) ? bias1[ncol] : bias2[ncol - split];
            #pragma unroll
            for (int i = 0; i < 4; ++i)
                #pragma unroll
                for (int r = 0; r < 4; ++r) {
                    int mrow = m0 + i * 16 + quad * 4 + r;
                    C[(size_t)mrow * NCOLS + ncol] = acc[i][t][r] + bv;
                }
        }
    }
}

// ---------------------------------------------------------------------------
// K2: MFMA-batched BiLSTM. Block = (dir, 16 sentences), 256 thr = 4 waves.
// M=16 rows = sentences; N=200 gates = 13 tiles split 4/3/3/3 per wave;
// K=50 padded 64 (2 chunks), split-bf16 3-term. W_hh frags register-resident.
//
// Round-2 redesign: NO global_load_lds (LDS-DMA forced the backend to insert
// conservative vmcnt waits before LDS reads — round-1 post-mortem).  Each
// gate-phase thread instead loads its own 4 xg scalars per step into a
// 2-slot REGISTER ring, issued 2 steps ahead; the backend's per-register
// scoreboard then emits precise counted vmcnt waits automatically.
// Cross-wave LDS handoffs (G, Ah/Al) use raw `s_waitcnt lgkmcnt(0);
// s_barrier` — vmcnt is never drained, so h->x stores and xg prefetch loads
// stay in flight across barriers (T4 semantics without fighting the
// compiler).
// ---------------------------------------------------------------------------
constexpr int WHC_DIR = 2 * 2 * 4 * 208 * 8;   // shorts per direction = 26624

__global__ __launch_bounds__(256)
void lstm_mfma(const float* __restrict__ xg, const unsigned short* __restrict__ Whc,
               float* __restrict__ x) {
    const int bi = blockIdx.x;
    const int dir = bi & 1;
    const int b0 = (bi >> 1) * 16;
    const int tid = threadIdx.x;
    const int w = tid >> 6, lane = tid & 63;
    const int r16 = lane & 15, quad = lane >> 4;

    __shared__ __align__(16) unsigned short Ah[8 * 16 * 8];  // [kq][s][8]
    __shared__ __align__(16) unsigned short Al[8 * 16 * 8];
    __shared__ __align__(16) float G[208 * 20];              // [gate][sent pad20]

    const int n0 = (w == 0) ? 0 : (w == 1) ? 4 : (w == 2) ? 7 : 10;
    const int nc = (w == 0) ? 4 : 3;

    const unsigned short* Wd = Whc + (size_t)dir * WHC_DIR;
    bf16x8 bfr[4][2][2];   // [tile][chunk][hi/lo]
    #pragma unroll
    for (int t = 0; t < 4; ++t) {
        int col = (n0 + ((t < nc) ? t : 0)) * 16 + r16;
        #pragma unroll
        for (int c = 0; c < 2; ++c)
            #pragma unroll
            for (int h = 0; h < 2; ++h)
                bfr[t][c][h] = *(const bf16x8*)&Wd[((((size_t)c * 2 + h) * 4 + quad) * 208 + col) * 8];
    }

    for (int q = tid; q < 512; q += 256) {
        ((unsigned*)Ah)[q] = 0u;
        ((unsigned*)Al)[q] = 0u;
    }

    int ss[4], ms[4];
    bool act[4];
    #pragma unroll
    for (int j = 0; j < 4; ++j) {
        int q = tid + 256 * j;
        ss[j] = q & 15;
        ms[j] = q >> 4;
        act[j] = (q < 800);
    }
    float c_reg[4] = {0.0f, 0.0f, 0.0f, 0.0f};

    // issue the 4 gate-input scalars per (s,m) item for `step` into xr
    auto issue = [&](int step, float (&xr)[4][4]) {
        const int idx = dir ? (63 - step) : step;
        const float* base = xg + (size_t)b0 * 25600 + (size_t)idx * 400 + dir * 200;
        #pragma unroll
        for (int j = 0; j < 4; ++j) {
            if (act[j]) {
                const float* p = base + (size_t)ss[j] * 25600 + ms[j];
                xr[j][0] = p[0];
                xr[j][1] = p[50];
                xr[j][2] = p[100];
                xr[j][3] = p[150];
            }
        }
    };

    auto do_step = [&](int step, float (&xcur)[4][4]) {
        const int idx = dir ? (63 - step) : step;
        // ---- MFMA phase: h(t-1) @ W_hh -> G ----
        bf16x8 ah[2], al[2];
        #pragma unroll
        for (int c = 0; c < 2; ++c) {
            ah[c] = *(const bf16x8*)&Ah[((c * 4 + quad) * 16 + r16) * 8];
            al[c] = *(const bf16x8*)&Al[((c * 4 + quad) * 16 + r16) * 8];
        }
        f32x4 acc[4] = {};
        #pragma unroll
        for (int t = 0; t < 4; ++t) {
            if (t < nc) {
                #pragma unroll
                for (int c = 0; c < 2; ++c) {
                    acc[t] = __builtin_amdgcn_mfma_f32_16x16x32_bf16(ah[c], bfr[t][c][0], acc[t], 0, 0, 0);
                    acc[t] = __builtin_amdgcn_mfma_f32_16x16x32_bf16(al[c], bfr[t][c][0], acc[t], 0, 0, 0);
                    acc[t] = __builtin_amdgcn_mfma_f32_16x16x32_bf16(ah[c], bfr[t][c][1], acc[t], 0, 0, 0);
                }
            }
        }
        #pragma unroll
        for (int t = 0; t < 4; ++t) {
            if (t < nc) {
                int col = (n0 + t) * 16 + r16;
                *(f32x4*)&G[col * 20 + quad * 4] = acc[t];
            }
        }
        // barrier #1: G visible (LDS only; vmcnt untouched)
        asm volatile("s_waitcnt lgkmcnt(0)\n\ts_barrier" ::: "memory");
        // ---- gate phase ----
        #pragma unroll
        for (int j = 0; j < 4; ++j) {
            if (act[j]) {
                int s = ss[j], m = ms[j];
                float gi = G[m * 20 + s]         + xcur[j][0];
                float gf = G[(m + 50) * 20 + s]  + xcur[j][1];
                float gg = G[(m + 100) * 20 + s] + xcur[j][2];
                float go = G[(m + 150) * 20 + s] + xcur[j][3];
                c_reg[j] = fsig2(gf) * c_reg[j] + fsig2(gi) * ftanh2(gg);
                float h = fsig2(go) * ftanh2(c_reg[j]);
                unsigned short hh, hl;
                split2(h, hh, hl);
                Ah[(m >> 3) * 128 + s * 8 + (m & 7)] = hh;
                Al[(m >> 3) * 128 + s * 8 + (m & 7)] = hl;
                x[((size_t)(b0 + s) * 64 + idx) * 100 + dir * 50 + m] = h;
            }
        }
        // refill the slot just consumed (for step+2); tail steps skip
        if (step < 62) issue(step + 2, xcur);
        // barrier #2: Ah/Al visible; stores/prefetch stay in flight
        asm volatile("s_waitcnt lgkmcnt(0)\n\ts_barrier" ::: "memory");
    };

    float xr0[4][4], xr1[4][4];
    issue(0, xr0);
    issue(1, xr1);
    __syncthreads();   // Ah/Al zero-init visible (also drains prologue loads)

    for (int s2 = 0; s2 < 32; ++s2) {
        do_step(2 * s2,     xr0);
        do_step(2 * s2 + 1, xr1);
    }
}

// ---------------------------------------------------------------------------
// K4: ChildSum TreeLSTM + masked pool + classifier. One block = one sentence.
// ---------------------------------------------------------------------------
__global__ __launch_bounds__(256)
void tree_kernel(const float* __restrict__ C2,
                 const float* __restrict__ Uw, const float* __restrict__ Ub,
                 const float* __restrict__ Fw, const float* __restrict__ Fb,
                 const float* __restrict__ tmask,
                 const float* __restrict__ Cw, const float* __restrict__ Cb,
                 float* __restrict__ out) {
    const int b = blockIdx.x;
    const int tid = threadIdx.x;

    __shared__ __align__(16) float h_sum[32][52];
    __shared__ __align__(16) float fc_sum[32][52];
    __shared__ __align__(16) float hcur[32][52];
    __shared__ __align__(16) float mcur[32][52];
    __shared__ float msg[16][152];
    __shared__ float hfin[64][50];
    __shared__ float pool[52];

    const int rU = (tid < 150) ? tid : 0;
    const int rF = tid % 50;
    float ur[50], fr[50];
    #pragma unroll
    for (int k = 0; k < 50; ++k) ur[k] = Uw[rU * 50 + k];
    #pragma unroll
    for (int k = 0; k < 50; ++k) fr[k] = Fw[rF * 50 + k];
    const float ub = Ub[rU];
    const float fb = Fb[rF];

    for (int q = tid; q < 32 * 52; q += 256) {
        h_sum[q / 52][q % 52] = 0.0f;
        fc_sum[q / 52][q % 52] = 0.0f;
    }
    __syncthreads();

    const float* c2b = C2 + (size_t)b * 64 * 200;

    for (int lvl = 6; lvl >= 0; --lvl) {
        const int lo = (1 << lvl) - 1;
        const int hi = min((1 << (lvl + 1)) - 2, 63);
        const int A = hi - lo + 1;
        const int chn = max(0, min(hi, 31) - lo + 1);

        if (tid < 150) {
            for (int a = 0; a < chn; ++a) {
                float acc = ub;
                #pragma unroll
                for (int k4 = 0; k4 < 12; ++k4) {
                    float4 h4 = *(const float4*)&h_sum[lo + a][k4 * 4];
                    acc += ur[k4*4+0]*h4.x + ur[k4*4+1]*h4.y + ur[k4*4+2]*h4.z + ur[k4*4+3]*h4.w;
                }
                acc += ur[48]*h_sum[lo + a][48] + ur[49]*h_sum[lo + a][49];
                msg[a][tid] = acc;
            }
        }
        __syncthreads();

        for (int q = tid; q < A * 50; q += 256) {
            int a = q / 50, m = q - a * 50;
            int loc = lo + a;
            const float* base = c2b + (size_t)loc * 200;
            bool ch = (a < chn);
            float ig = base[m]       + (ch ? msg[a][m]       : 0.0f);
            float og = base[50 + m]  + (ch ? msg[a][50 + m]  : 0.0f);
            float ug = base[100 + m] + (ch ? msg[a][100 + m] : 0.0f);
            float cn = fsig(ig) * ftanh(ug) + (ch ? fc_sum[loc][m] : 0.0f);
            float hn = base[150 + m] + fsig(og) * ftanh(cn);
            hcur[a][m] = hn;
            mcur[a][m] = cn;
            hfin[loc][m] = hn;
        }
        __syncthreads();

        if (tid < 250) {
            for (int a = tid / 50; a < A; a += 5) {
                float acc = fb;
                #pragma unroll
                for (int k4 = 0; k4 < 12; ++k4) {
                    float4 h4 = *(const float4*)&hcur[a][k4 * 4];
                    acc += fr[k4*4+0]*h4.x + fr[k4*4+1]*h4.y + fr[k4*4+2]*h4.z + fr[k4*4+3]*h4.w;
                }
                acc += fr[48]*hcur[a][48] + fr[49]*hcur[a][49];
                mcur[a][rF] = fsig(acc) * mcur[a][rF];
            }
        }
        __syncthreads();

        if (lvl > 0) {
            const int plo = (lo - 1) >> 1, phi = (hi - 1) >> 1;
            const int P = phi - plo + 1;
            for (int q = tid; q < P * 50; q += 256) {
                int pi = q / 50, m = q - pi * 50;
                int p = plo + pi;
                int c1 = 2 * p + 1, c2i = 2 * p + 2;
                float hs = hcur[c1 - lo][m];
                float fs = mcur[c1 - lo][m];
                if (c2i <= hi) { hs += hcur[c2i - lo][m]; fs += mcur[c2i - lo][m]; }
                h_sum[p][m] += hs;
                fc_sum[p][m] += fs;
            }
        }
        __syncthreads();
    }

    const float* tm = tmask + (size_t)b * 64;
    if (tid < 50) {
        float acc = 0.0f, ws = 0.0f;
        for (int l = 0; l < 64; ++l) {
            float wv = tm[l];
            ws += wv;
            acc += wv * hfin[l][tid];
        }
        float p = acc / ws;
        pool[tid] = p;
        out[3072 + (size_t)b * 50 + tid] = p;
    }
    __syncthreads();
    if (tid < 3) {
        float acc = Cb[tid];
        #pragma unroll
        for (int m = 0; m < 50; ++m) acc += Cw[tid * 50 + m] * pool[m];
        out[(size_t)b * 3 + tid] = acc;
    }
}

// ---------------------------------------------------------------------------
extern "C" void kernel_launch(void* const* d_in, const int* in_sizes, int n_in,
                              void* d_out, int out_size, void* d_ws, size_t ws_size,
                              hipStream_t stream) {
    (void)in_sizes; (void)n_in; (void)out_size; (void)ws_size;
    const int*   ids   = (const int*)d_in[0];
    const float* tmask = (const float*)d_in[3];
    const float* table = (const float*)d_in[5];
    const float* Wihf  = (const float*)d_in[6];
    const float* Whhf  = (const float*)d_in[7];
    const float* bf    = (const float*)d_in[8];
    const float* Wihb  = (const float*)d_in[9];
    const float* Whhb  = (const float*)d_in[10];
    const float* bb    = (const float*)d_in[11];
    const float* Wiou  = (const float*)d_in[12];
    const float* Uiouw = (const float*)d_in[13];
    const float* Uioub = (const float*)d_in[14];
    const float* biou  = (const float*)d_in[15];
    const float* Ufw   = (const float*)d_in[16];
    const float* Ufb   = (const float*)d_in[17];
    const float* Hw    = (const float*)d_in[18];
    const float* Hb    = (const float*)d_in[19];
    const float* Cw    = (const float*)d_in[20];
    const float* Cb    = (const float*)d_in[21];
    float* out = (float*)d_out;

    float* wsf = (float*)d_ws;
    float* xg = wsf;                                  // 65536*400 f32 (C2 later)
    float* x  = wsf + (size_t)65536 * 400;            // 65536*100 f32
    float* C2 = wsf;
    unsigned short* B1c = (unsigned short*)(wsf + 32768000);  // 10*2*4*448*8 ush
    unsigned short* B3c = (unsigned short*)(wsf + 32911360);  // 4*2*4*256*8 ush
    unsigned short* Whc = (unsigned short*)(wsf + 32944128);  // 2 * WHC_DIR ush

    // K0: weight pre-conversion (hi|lo bf16, chunked layout)
    conv_kernel<<<70, 256, 0, stream>>>(Wihf, Wihb, 200, 300, 400, 448, 10, B1c);
    conv_kernel<<<16, 256, 0, stream>>>(Wiou, Hw, 150, 100, 200, 256, 4, B3c);
    conv_kernel<<<7, 256, 0, stream>>>(Whhf, Whhf, 200, 50, 200, 208, 2, Whc);
    conv_kernel<<<7, 256, 0, stream>>>(Whhb, Whhb, 200, 50, 200, 208, 2, Whc + WHC_DIR);
    // K1: xg = gather(embed)@[W_ih_f;W_ih_b]^T + bias   (N x 400)
    gemm_split<448, 10, 300, 400, true><<<1024, 256, 0, stream>>>(
        table, ids, B1c, bf, bb, 200, xg);
    // K2: MFMA BiLSTM -> x (N x 100) = [hf | hb]
    lstm_mfma<<<128, 256, 0, stream>>>(xg, Whc, x);
    // K3: C2 = x@[W_iou^T | H_w^T] + [b_iou | H_b]   (N x 200)
    gemm_split<256, 4, 100, 200, false><<<1024, 256, 0, stream>>>(
        x, nullptr, B3c, biou, Hb, 150, C2);
    // K4: TreeLSTM + pool + classifier
    tree_kernel<<<1024, 256, 0, stream>>>(
        C2, Uiouw, Uioub, Ufw, Ufb, tmask, Cw, Cb, out);
}

// Round 3
// 450.743 us; speedup vs baseline: 1.1645x; 1.1645x over previous
//
#include <hip/hip_runtime.h>

// Problem constants: B=1024, L=64, N=65536, V=100000, E=300, RH=M=50, NC=3
// tree: balanced binary, parent=(i-1)//2, depths 0..6, locs 0..31 have children

typedef __attribute__((ext_vector_type(8))) short bf16x8;
typedef __attribute__((ext_vector_type(4))) float f32x4;

// ---- activations ----
__device__ __forceinline__ float fsig(float x) { return 1.0f / (1.0f + __expf(-x)); }
__device__ __forceinline__ float ftanh(float x) {
    float a = fabsf(x);
    float t = __expf(2.0f * a);
    float r = 1.0f - 2.0f / (t + 1.0f);
    return copysignf(r, x);
}
__device__ __forceinline__ float fsig2(float x) {
    float e = __builtin_amdgcn_exp2f(-1.4426950408889634f * x);
    return __builtin_amdgcn_rcpf(1.0f + e);
}
__device__ __forceinline__ float ftanh2(float x) {
    float e = __builtin_amdgcn_exp2f(2.8853900817779268f * x);
    return 1.0f - 2.0f * __builtin_amdgcn_rcpf(1.0f + e);
}

// round-to-nearest-even f32 -> bf16 (returns upper 16 bits)
__device__ __forceinline__ unsigned short rne_bf16(float f) {
    unsigned u = __builtin_bit_cast(unsigned, f);
    unsigned r = u + 0x7fffu + ((u >> 16) & 1u);
    return (unsigned short)(r >> 16);
}
// fp32 -> bf16 hi + bf16 lo (RNE both limbs; combined residual ~2^-17 rel, unbiased)
__device__ __forceinline__ void split2(float f, unsigned short& h, unsigned short& l) {
    h = rne_bf16(f);
    float fh = __builtin_bit_cast(float, ((unsigned)h) << 16);
    float r = f - fh;   // exact (Sterbenz)
    l = rne_bf16(r);
}

__device__ __forceinline__ void async_lds16(const void* g, void* l) {
    __builtin_amdgcn_global_load_lds(
        (const __attribute__((address_space(1))) unsigned int*)g,
        (__attribute__((address_space(3))) unsigned int*)l, 16, 0, 0);
}

__device__ __forceinline__ bf16x8 pack8(const unsigned short* h) {
    bf16x8 v;
    #pragma unroll
    for (int e = 0; e < 8; ++e) v[e] = (short)h[e];
    return v;
}

// ---------------------------------------------------------------------------
// K0: convert weights [B1;B2] (rows = output cols, K contraction) to chunked
// hi|lo bf16 layout: out[(((c*2+h)*4 + kq)*BN + n)*8 + e] covers
// k = c*32 + kq*8 + e.  n >= Rreal or k >= K zero-filled.
// Linear per chunk (async-copyable) AND lane-consecutive for frag reads.
// Total size per call: KCH*2*4*BN*8 shorts.
// ---------------------------------------------------------------------------
__global__ void conv_kernel(const float* __restrict__ B1, const float* __restrict__ B2,
                            int split, int K, int Rreal, int BN, int KCH,
                            unsigned short* __restrict__ out) {
    int q = blockIdx.x * 256 + threadIdx.x;
    int total = KCH * 4 * BN;
    if (q >= total) return;
    int n  = q % BN;
    int kq = (q / BN) & 3;
    int c  = q / (BN * 4);
    const float* row = (n < split) ? (B1 + (size_t)n * K) : (B2 + (size_t)(n - split) * K);
    unsigned short h[8], l[8];
    #pragma unroll
    for (int e = 0; e < 8; ++e) {
        int k = c * 32 + kq * 8 + e;
        float v = (n < Rreal && k < K) ? row[k] : 0.0f;
        split2(v, h[e], l[e]);
    }
    size_t hb = ((((size_t)c * 2 + 0) * 4 + kq) * BN + n) * 8;
    size_t lb = ((((size_t)c * 2 + 1) * 4 + kq) * BN + n) * 8;
    *(ushort4*)&out[hb]     = make_ushort4(h[0], h[1], h[2], h[3]);
    *(ushort4*)&out[hb + 4] = make_ushort4(h[4], h[5], h[6], h[7]);
    *(ushort4*)&out[lb]     = make_ushort4(l[0], l[1], l[2], l[3]);
    *(ushort4*)&out[lb + 4] = make_ushort4(l[4], l[5], l[6], l[7]);
}

// ---------------------------------------------------------------------------
// Split-bf16 MFMA GEMM. BM=64 rows, BN padded cols, 256 thr = 4 waves
// column-split. Conflict-free LDS: A [h][kq][64][8], B [h][kq][BN][8]
// (pre-converted, async-staged). 3 mfma terms: Ah*Bh + Al*Bh + Ah*Bl.
// ---------------------------------------------------------------------------
template<int BN, int KCH, int KREAL, int NCOLS, bool GATHER>
__global__ __launch_bounds__(256)
void gemm_split(const float* __restrict__ A, const int* __restrict__ ids,
                const unsigned short* __restrict__ Bc,
                const float* __restrict__ bias1, const float* __restrict__ bias2,
                int split, float* __restrict__ C) {
    constexpr int NTW = BN / 64;   // 16-col tiles per wave
    __shared__ __align__(16) unsigned short As[2 * 4 * 64 * 8];  // 8 KB
    __shared__ __align__(16) unsigned short Bt[64 * BN];

    const int tid = threadIdx.x;
    const int m0 = blockIdx.x * 64;
    const int w = tid >> 6, lane = tid & 63;
    const int r16 = lane & 15, quad = lane >> 4;
    const int wn = w * (BN / 4);

    const int mA = tid & 63, kqA = tid >> 6;
    const float* arow = GATHER ? (A + (size_t)ids[m0 + mA] * KREAL)
                               : (A + (size_t)(m0 + mA) * KREAL);

    float ar[8];
    {
        int k0 = kqA * 8;
        if (k0 + 8 <= KREAL) {
            float4 p = *(const float4*)(arow + k0);
            float4 q = *(const float4*)(arow + k0 + 4);
            ar[0]=p.x; ar[1]=p.y; ar[2]=p.z; ar[3]=p.w;
            ar[4]=q.x; ar[5]=q.y; ar[6]=q.z; ar[7]=q.w;
        } else {
            #pragma unroll
            for (int e = 0; e < 8; ++e) ar[e] = (k0 + e < KREAL) ? arow[k0 + e] : 0.0f;
        }
    }

    f32x4 acc[4][NTW] = {};

    for (int c = 0; c < KCH; ++c) {
        __syncthreads();
        {
            const unsigned short* src = Bc + (size_t)c * 64 * BN + tid * 8;
            #pragma unroll
            for (int i = 0; i < BN / 32; ++i)
                async_lds16(src + (size_t)i * 2048, Bt + i * 2048 + tid * 8);
        }
        {
            unsigned short h[8], l[8];
            #pragma unroll
            for (int e = 0; e < 8; ++e) split2(ar[e], h[e], l[e]);
            *(bf16x8*)&As[((0 * 4 + kqA) * 64 + mA) * 8] = pack8(h);
            *(bf16x8*)&As[((1 * 4 + kqA) * 64 + mA) * 8] = pack8(l);
        }
        __syncthreads();
        if (c + 1 < KCH) {
            int k0 = (c + 1) * 32 + kqA * 8;
            if (k0 + 8 <= KREAL) {
                float4 p = *(const float4*)(arow + k0);
                float4 q = *(const float4*)(arow + k0 + 4);
                ar[0]=p.x; ar[1]=p.y; ar[2]=p.z; ar[3]=p.w;
                ar[4]=q.x; ar[5]=q.y; ar[6]=q.z; ar[7]=q.w;
            } else {
                #pragma unroll
                for (int e = 0; e < 8; ++e) ar[e] = (k0 + e < KREAL) ? arow[k0 + e] : 0.0f;
            }
        }
        bf16x8 af[2][4];
        #pragma unroll
        for (int i = 0; i < 4; ++i) {
            af[0][i] = *(const bf16x8*)&As[((0 * 4 + quad) * 64 + i * 16 + r16) * 8];
            af[1][i] = *(const bf16x8*)&As[((1 * 4 + quad) * 64 + i * 16 + r16) * 8];
        }
        #pragma unroll
        for (int t = 0; t < NTW; ++t) {
            bf16x8 bh = *(const bf16x8*)&Bt[((0 * 4 + quad) * BN + wn + t * 16 + r16) * 8];
            bf16x8 bl = *(const bf16x8*)&Bt[((1 * 4 + quad) * BN + wn + t * 16 + r16) * 8];
            #pragma unroll
            for (int i = 0; i < 4; ++i) {
                acc[i][t] = __builtin_amdgcn_mfma_f32_16x16x32_bf16(af[0][i], bh, acc[i][t], 0, 0, 0);
                acc[i][t] = __builtin_amdgcn_mfma_f32_16x16x32_bf16(af[1][i], bh, acc[i][t], 0, 0, 0);
                acc[i][t] = __builtin_amdgcn_mfma_f32_16x16x32_bf16(af[0][i], bl, acc[i][t], 0, 0, 0);
            }
        }
    }

    #pragma unroll
    for (int t = 0; t < NTW; ++t) {
        int ncol = wn + t * 16 + r16;
        if (ncol < NCOLS) {
            float bv = (ncol < split) ? bias1[ncol] : bias2[ncol - split];
            #pragma unroll
            for (int i = 0; i < 4; ++i)
                #pragma unroll
                for (int r = 0; r < 4; ++r) {
                    int mrow = m0 + i * 16 + quad * 4 + r;
                    C[(size_t)mrow * NCOLS + ncol] = acc[i][t][r] + bv;
                }
        }
    }
}

// ---------------------------------------------------------------------------
// K2: MFMA-batched BiLSTM. Block = (dir, 16 sentences), 256 thr = 4 waves.
// M=16 rows = sentences; N=200 gates = 13 tiles split 4/3/3/3 per wave;
// K=50 padded 64 (2 chunks), split-bf16 3-term. W_hh frags register-resident.
// h round-trips LDS [kq][sent][8]; xg prefetched 2 steps ahead (ring of 3)
// via global_load_lds.
//
// Counted-vmcnt sync (T3/T4), round-3 fix: per-wave VMEM instruction counts
// are UNIFORM — gate items are assigned q = w*200 + lane + 64*j (j=0..3,
// j=3 active for lane<8), so EVERY wave issues exactly 4 h-stores + 4 DMA
// loads per step.  vmcnt counts per-wave instructions; round-1's
// tid+256*j mapping gave wave 0 four stores but waves 1-3 three, making
// vmcnt(14) wait on two scattered store-acks every step (the 89->118
// regression).
// Audit at barrier #1 of step t (need L_t = P_{t-2} landed):
//   ops newer than P_{t-2}: S_{t-2}(4) + P_{t-1}(4) + S_{t-1}(4) + P_t(4)
//   = 16 for every wave -> s_waitcnt vmcnt(16) waits for exactly L_t.
// Stores are never waited on; prefetch loads stay in flight across both
// barriers.  Tail steps issue clamped dummy loads (dead or identical-value
// slots) to keep the count uniform.  Prologue __syncthreads() drains L_0,
// L_1 so steps 0..1 are trivially safe.
// ---------------------------------------------------------------------------
constexpr int WHC_DIR = 2 * 2 * 4 * 208 * 8;   // shorts per direction = 26624

__global__ __launch_bounds__(256)
void lstm_mfma(const float* __restrict__ xg, const unsigned short* __restrict__ Whc,
               float* __restrict__ x) {
    const int bi = blockIdx.x;
    const int dir = bi & 1;
    const int b0 = (bi >> 1) * 16;
    const int tid = threadIdx.x;
    const int w = tid >> 6, lane = tid & 63;
    const int r16 = lane & 15, quad = lane >> 4;

    __shared__ __align__(16) unsigned short Ah[8 * 16 * 8];  // [kq][s][8]
    __shared__ __align__(16) unsigned short Al[8 * 16 * 8];
    __shared__ __align__(16) float G[208 * 20];              // [gate][sent pad20]
    __shared__ __align__(16) float Xs[3][16][268];           // xg ring (lead 2)

    const int n0 = (w == 0) ? 0 : (w == 1) ? 4 : (w == 2) ? 7 : 10;
    const int nc = (w == 0) ? 4 : 3;

    const unsigned short* Wd = Whc + (size_t)dir * WHC_DIR;
    bf16x8 bfr[4][2][2];   // [tile][chunk][hi/lo]
    #pragma unroll
    for (int t = 0; t < 4; ++t) {
        int col = (n0 + ((t < nc) ? t : 0)) * 16 + r16;
        #pragma unroll
        for (int c = 0; c < 2; ++c)
            #pragma unroll
            for (int h = 0; h < 2; ++h)
                bfr[t][c][h] = *(const bf16x8*)&Wd[((((size_t)c * 2 + h) * 4 + quad) * 208 + col) * 8];
    }

    for (int q = tid; q < 512; q += 256) {
        ((unsigned*)Ah)[q] = 0u;
        ((unsigned*)Al)[q] = 0u;
    }

    // gate-item mapping: q = w*200 + lane + 64*j  (uniform 4 store instrs/wave)
    int ss[4], ms[4];
    bool act[4];
    #pragma unroll
    for (int j = 0; j < 4; ++j) {
        int q = w * 200 + lane + 64 * j;
        ss[j] = q & 15;
        ms[j] = q >> 4;
        act[j] = (lane + 64 * j) < 200;
    }
    float c_reg[4] = {0.0f, 0.0f, 0.0f, 0.0f};

    // prologue: steps 0 and 1 into ring slots 0,1 (drained by __syncthreads)
    #pragma unroll
    for (int p = 0; p < 2; ++p) {
        int idx0 = dir ? (63 - p) : p;
        #pragma unroll
        for (int i = 0; i < 4; ++i) {
            int s = w * 4 + i;
            const float* src = xg + ((size_t)(b0 + s) * 64 + idx0) * 400 + dir * 200 + lane * 4;
            async_lds16(src, &Xs[p][s][lane * 4]);
        }
    }
    __syncthreads();

    for (int step = 0; step < 64; ++step) {
        const int buf = step % 3;
        const int idx = dir ? (63 - step) : step;
        {
            // issue prefetch for step+2 (clamped dummy reload at the tail to
            // keep the per-step vmem instruction count uniform)
            int stepn = step + 2; if (stepn > 63) stepn = 63;
            const int slot = (step + 2) % 3;
            const int idxn = dir ? (63 - stepn) : stepn;
            #pragma unroll
            for (int i = 0; i < 4; ++i) {
                int s = w * 4 + i;
                const float* src = xg + ((size_t)(b0 + s) * 64 + idxn) * 400 + dir * 200 + lane * 4;
                async_lds16(src, &Xs[slot][s][lane * 4]);
            }
            __builtin_amdgcn_sched_barrier(0);   // pin issue before the counted wait
        }
        bf16x8 ah[2], al[2];
        #pragma unroll
        for (int c = 0; c < 2; ++c) {
            ah[c] = *(const bf16x8*)&Ah[((c * 4 + quad) * 16 + r16) * 8];
            al[c] = *(const bf16x8*)&Al[((c * 4 + quad) * 16 + r16) * 8];
        }
        f32x4 acc[4] = {};
        #pragma unroll
        for (int t = 0; t < 4; ++t) {
            if (t < nc) {
                #pragma unroll
                for (int c = 0; c < 2; ++c) {
                    acc[t] = __builtin_amdgcn_mfma_f32_16x16x32_bf16(ah[c], bfr[t][c][0], acc[t], 0, 0, 0);
                    acc[t] = __builtin_amdgcn_mfma_f32_16x16x32_bf16(al[c], bfr[t][c][0], acc[t], 0, 0, 0);
                    acc[t] = __builtin_amdgcn_mfma_f32_16x16x32_bf16(ah[c], bfr[t][c][1], acc[t], 0, 0, 0);
                }
            }
        }
        #pragma unroll
        for (int t = 0; t < 4; ++t) {
            if (t < nc) {
                int col = (n0 + t) * 16 + r16;
                *(f32x4*)&G[col * 20 + quad * 4] = acc[t];
            }
        }
        // barrier #1: G visible to all waves; own L_t landed via counted
        // vmcnt(16) (exact for every wave — uniform instruction counts);
        // cross-wave Xs coverage comes from the barrier itself.
        asm volatile("s_waitcnt lgkmcnt(0) vmcnt(16)" ::: "memory");
        __builtin_amdgcn_sched_barrier(0);
        __builtin_amdgcn_s_barrier();
        __builtin_amdgcn_sched_barrier(0);
        #pragma unroll
        for (int j = 0; j < 4; ++j) {
            if (act[j]) {
                int s = ss[j], m = ms[j];
                float gi = G[m * 20 + s]         + Xs[buf][s][m];
                float gf = G[(m + 50) * 20 + s]  + Xs[buf][s][m + 50];
                float gg = G[(m + 100) * 20 + s] + Xs[buf][s][m + 100];
                float go = G[(m + 150) * 20 + s] + Xs[buf][s][m + 150];
                c_reg[j] = fsig2(gf) * c_reg[j] + fsig2(gi) * ftanh2(gg);
                float h = fsig2(go) * ftanh2(c_reg[j]);
                unsigned short hh, hl;
                split2(h, hh, hl);
                Ah[(m >> 3) * 128 + s * 8 + (m & 7)] = hh;
                Al[(m >> 3) * 128 + s * 8 + (m & 7)] = hl;
                x[((size_t)(b0 + s) * 64 + idx) * 100 + dir * 50 + m] = h;
            }
        }
        // barrier #2: Ah/Al visible; h-stores/prefetch stay in flight.
        asm volatile("s_waitcnt lgkmcnt(0)" ::: "memory");
        __builtin_amdgcn_sched_barrier(0);
        __builtin_amdgcn_s_barrier();
        __builtin_amdgcn_sched_barrier(0);
    }
}

// ---------------------------------------------------------------------------
// K4: ChildSum TreeLSTM + masked pool + classifier. One block = one sentence.
// ---------------------------------------------------------------------------
__global__ __launch_bounds__(256)
void tree_kernel(const float* __restrict__ C2,
                 const float* __restrict__ Uw, const float* __restrict__ Ub,
                 const float* __restrict__ Fw, const float* __restrict__ Fb,
                 const float* __restrict__ tmask,
                 const float* __restrict__ Cw, const float* __restrict__ Cb,
                 float* __restrict__ out) {
    const int b = blockIdx.x;
    const int tid = threadIdx.x;

    __shared__ __align__(16) float h_sum[32][52];
    __shared__ __align__(16) float fc_sum[32][52];
    __shared__ __align__(16) float hcur[32][52];
    __shared__ __align__(16) float mcur[32][52];
    __shared__ float msg[16][152];
    __shared__ float hfin[64][50];
    __shared__ float pool[52];

    const int rU = (tid < 150) ? tid : 0;
    const int rF = tid % 50;
    float ur[50], fr[50];
    #pragma unroll
    for (int k = 0; k < 50; ++k) ur[k] = Uw[rU * 50 + k];
    #pragma unroll
    for (int k = 0; k < 50; ++k) fr[k] = Fw[rF * 50 + k];
    const float ub = Ub[rU];
    const float fb = Fb[rF];

    for (int q = tid; q < 32 * 52; q += 256) {
        h_sum[q / 52][q % 52] = 0.0f;
        fc_sum[q / 52][q % 52] = 0.0f;
    }
    __syncthreads();

    const float* c2b = C2 + (size_t)b * 64 * 200;

    for (int lvl = 6; lvl >= 0; --lvl) {
        const int lo = (1 << lvl) - 1;
        const int hi = min((1 << (lvl + 1)) - 2, 63);
        const int A = hi - lo + 1;
        const int chn = max(0, min(hi, 31) - lo + 1);

        if (tid < 150) {
            for (int a = 0; a < chn; ++a) {
                float acc = ub;
                #pragma unroll
                for (int k4 = 0; k4 < 12; ++k4) {
                    float4 h4 = *(const float4*)&h_sum[lo + a][k4 * 4];
                    acc += ur[k4*4+0]*h4.x + ur[k4*4+1]*h4.y + ur[k4*4+2]*h4.z + ur[k4*4+3]*h4.w;
                }
                acc += ur[48]*h_sum[lo + a][48] + ur[49]*h_sum[lo + a][49];
                msg[a][tid] = acc;
            }
        }
        __syncthreads();

        for (int q = tid; q < A * 50; q += 256) {
            int a = q / 50, m = q - a * 50;
            int loc = lo + a;
            const float* base = c2b + (size_t)loc * 200;
            bool ch = (a < chn);
            float ig = base[m]       + (ch ? msg[a][m]       : 0.0f);
            float og = base[50 + m]  + (ch ? msg[a][50 + m]  : 0.0f);
            float ug = base[100 + m] + (ch ? msg[a][100 + m] : 0.0f);
            float cn = fsig(ig) * ftanh(ug) + (ch ? fc_sum[loc][m] : 0.0f);
            float hn = base[150 + m] + fsig(og) * ftanh(cn);
            hcur[a][m] = hn;
            mcur[a][m] = cn;
            hfin[loc][m] = hn;
        }
        __syncthreads();

        if (tid < 250) {
            for (int a = tid / 50; a < A; a += 5) {
                float acc = fb;
                #pragma unroll
                for (int k4 = 0; k4 < 12; ++k4) {
                    float4 h4 = *(const float4*)&hcur[a][k4 * 4];
                    acc += fr[k4*4+0]*h4.x + fr[k4*4+1]*h4.y + fr[k4*4+2]*h4.z + fr[k4*4+3]*h4.w;
                }
                acc += fr[48]*hcur[a][48] + fr[49]*hcur[a][49];
                mcur[a][rF] = fsig(acc) * mcur[a][rF];
            }
        }
        __syncthreads();

        if (lvl > 0) {
            const int plo = (lo - 1) >> 1, phi = (hi - 1) >> 1;
            const int P = phi - plo + 1;
            for (int q = tid; q < P * 50; q += 256) {
                int pi = q / 50, m = q - pi * 50;
                int p = plo + pi;
                int c1 = 2 * p + 1, c2i = 2 * p + 2;
                float hs = hcur[c1 - lo][m];
                float fs = mcur[c1 - lo][m];
                if (c2i <= hi) { hs += hcur[c2i - lo][m]; fs += mcur[c2i - lo][m]; }
                h_sum[p][m] += hs;
                fc_sum[p][m] += fs;
            }
        }
        __syncthreads();
    }

    const float* tm = tmask + (size_t)b * 64;
    if (tid < 50) {
        float acc = 0.0f, ws = 0.0f;
        for (int l = 0; l < 64; ++l) {
            float wv = tm[l];
            ws += wv;
            acc += wv * hfin[l][tid];
        }
        float p = acc / ws;
        pool[tid] = p;
        out[3072 + (size_t)b * 50 + tid] = p;
    }
    __syncthreads();
    if (tid < 3) {
        float acc = Cb[tid];
        #pragma unroll
        for (int m = 0; m < 50; ++m) acc += Cw[tid * 50 + m] * pool[m];
        out[(size_t)b * 3 + tid] = acc;
    }
}

// ---------------------------------------------------------------------------
extern "C" void kernel_launch(void* const* d_in, const int* in_sizes, int n_in,
                              void* d_out, int out_size, void* d_ws, size_t ws_size,
                              hipStream_t stream) {
    (void)in_sizes; (void)n_in; (void)out_size; (void)ws_size;
    const int*   ids   = (const int*)d_in[0];
    const float* tmask = (const float*)d_in[3];
    const float* table = (const float*)d_in[5];
    const float* Wihf  = (const float*)d_in[6];
    const float* Whhf  = (const float*)d_in[7];
    const float* bf    = (const float*)d_in[8];
    const float* Wihb  = (const float*)d_in[9];
    const float* Whhb  = (const float*)d_in[10];
    const float* bb    = (const float*)d_in[11];
    const float* Wiou  = (const float*)d_in[12];
    const float* Uiouw = (const float*)d_in[13];
    const float* Uioub = (const float*)d_in[14];
    const float* biou  = (const float*)d_in[15];
    const float* Ufw   = (const float*)d_in[16];
    const float* Ufb   = (const float*)d_in[17];
    const float* Hw    = (const float*)d_in[18];
    const float* Hb    = (const float*)d_in[19];
    const float* Cw    = (const float*)d_in[20];
    const float* Cb    = (const float*)d_in[21];
    float* out = (float*)d_out;

    float* wsf = (float*)d_ws;
    float* xg = wsf;                                  // 65536*400 f32 (C2 later)
    float* x  = wsf + (size_t)65536 * 400;            // 65536*100 f32
    float* C2 = wsf;
    unsigned short* B1c = (unsigned short*)(wsf + 32768000);  // 10*2*4*448*8 ush
    unsigned short* B3c = (unsigned short*)(wsf + 32911360);  // 4*2*4*256*8 ush
    unsigned short* Whc = (unsigned short*)(wsf + 32944128);  // 2 * WHC_DIR ush

    // K0: weight pre-conversion (hi|lo bf16, chunked layout)
    conv_kernel<<<70, 256, 0, stream>>>(Wihf, Wihb, 200, 300, 400, 448, 10, B1c);
    conv_kernel<<<16, 256, 0, stream>>>(Wiou, Hw, 150, 100, 200, 256, 4, B3c);
    conv_kernel<<<7, 256, 0, stream>>>(Whhf, Whhf, 200, 50, 200, 208, 2, Whc);
    conv_kernel<<<7, 256, 0, stream>>>(Whhb, Whhb, 200, 50, 200, 208, 2, Whc + WHC_DIR);
    // K1: xg = gather(embed)@[W_ih_f;W_ih_b]^T + bias   (N x 400)
    gemm_split<448, 10, 300, 400, true><<<1024, 256, 0, stream>>>(
        table, ids, B1c, bf, bb, 200, xg);
    // K2: MFMA BiLSTM -> x (N x 100) = [hf | hb]
    lstm_mfma<<<128, 256, 0, stream>>>(xg, Whc, x);
    // K3: C2 = x@[W_iou^T | H_w^T] + [b_iou | H_b]   (N x 200)
    gemm_split<256, 4, 100, 200, false><<<1024, 256, 0, stream>>>(
        x, nullptr, B3c, biou, Hb, 150, C2);
    // K4: TreeLSTM + pool + classifier
    tree_kernel<<<1024, 256, 0, stream>>>(
        C2, Uiouw, Uioub, Ufw, Ufb, tmask, Cw, Cb, out);
}